// Round 1
// baseline (1574.718 us; speedup 1.0000x reference)
//
#include <hip/hip_runtime.h>

// PairwiseScore: out[pair] = MLP([g_i, g_j, g_i*g_j]) with
//   h1pre = g_i@W1a + g_j@W1b + (g_i*g_j)@W1c + b1   (W1 split into 3 x [1200,150])
// A = G@W1a + b1 and B = G@W1b precomputed per pruned mention (2000 rows).
// Shapes fixed by the harness: M=10000, D=1200, P=2000, K=50, H=150, NP=98725.

constexpr int Dd   = 1200;   // G_DIM
constexpr int Hh   = 150;    // HIDDEN
constexpr int HP   = 152;    // padded H (multiple of 8)
constexpr int NJG  = 13;     // j-groups (4 j each -> 52 j slots)
constexpr int NHG  = 19;     // h-groups (8 h each -> 152 h slots)
constexpr int JP   = 52;     // NJG*4
constexpr int DC   = 64;     // d-chunk, layer 1
constexpr int DC2  = 32;     // d-chunk, layer 2
constexpr int NCH  = (Dd + DC - 1) / DC;    // 19
constexpr int NCH2 = (HP + DC2 - 1) / DC2;  // 5

// LDS arena layout (floats):
// phase 1: gi[1200] @0 | Xt[DC][JP] @1200 | Wc[DC][HP] @4528   -> 14256 total
// phase 2: H1t[HP][JP] @0 (7904) | Wc2[DC2][HP] @7904 (4864)   -> 12768
// phase 3: red[NHG][JP] @0 (988)
constexpr int XT_OFF  = Dd;
constexpr int WC_OFF  = Dd + DC * JP;       // 4528
constexpr int ARENA   = Dd + DC * JP + DC * HP;  // 14256 floats = 57KB
constexpr int WC2_OFF = HP * JP;            // 7904
static_assert(WC2_OFF + DC2 * HP <= ARENA, "arena too small");

__device__ __forceinline__ void fma_tile(float (&acc)[4][8], const float4 xv,
                                         const float4 wa, const float4 wb) {
  const float xj[4] = {xv.x, xv.y, xv.z, xv.w};
  const float wh[8] = {wa.x, wa.y, wa.z, wa.w, wb.x, wb.y, wb.z, wb.w};
#pragma unroll
  for (int jj = 0; jj < 4; ++jj)
#pragma unroll
    for (int hh = 0; hh < 8; ++hh)
      acc[jj][hh] = fmaf(xj[jj], wh[hh], acc[jj][hh]);
}

// ---------------- kernel 0: gather G = mention_reprs[pruned_idx] ----------------
__global__ void k_gather(const float* __restrict__ M, const int* __restrict__ pidx,
                         float* __restrict__ G) {
  const int i = blockIdx.x;
  const int r = pidx[i];
  const float4* src = reinterpret_cast<const float4*>(M + (size_t)r * Dd);
  float4* dst = reinterpret_cast<float4*>(G + (size_t)i * Dd);
  for (int t = threadIdx.x; t < Dd / 4; t += blockDim.x) dst[t] = src[t];
}

// ------------- kernel 1: AB[part][r][h] = G[r,:] @ W1[part*1200:,:][:,h] -------------
// part 0 adds b1.  Pad cols (h>=150) written as 0.
__global__ __launch_bounds__(256) void k_precomp(const float* __restrict__ G,
                                                 const float* __restrict__ W1,
                                                 const float* __restrict__ b1,
                                                 float* __restrict__ AB, int P) {
  __shared__ __align__(16) float sX[DC * JP];
  __shared__ __align__(16) float sW[DC * HP];
  const int r0 = blockIdx.x * JP;
  const int part = blockIdx.y;
  const float* Wbase = W1 + (size_t)part * Dd * Hh;
  float* outp = AB + (size_t)part * (size_t)P * HP;

  const int tid = threadIdx.x;
  const int jg = tid % NJG, hg = tid / NJG;
  const bool active = hg < NHG;
  const int j0 = jg * 4, h0 = hg * 8;
  float acc[4][8] = {};

  for (int c = 0; c < NCH; ++c) {
    const int d0 = c * DC;
    for (int t = tid; t < DC * HP; t += 256) {
      const int dl = t / HP, h = t - dl * HP;
      const int d = d0 + dl;
      sW[t] = (h < Hh && d < Dd) ? Wbase[(size_t)d * Hh + h] : 0.f;
    }
    for (int t = tid; t < JP * DC; t += 256) {
      const int j = t >> 6, dl = t & (DC - 1);
      const int r = r0 + j, d = d0 + dl;
      sX[dl * JP + j] = (r < P && d < Dd) ? G[(size_t)r * Dd + d] : 0.f;
    }
    __syncthreads();
    if (active) {
#pragma unroll 4
      for (int dl = 0; dl < DC; ++dl) {
        const float4 xv = *reinterpret_cast<const float4*>(&sX[dl * JP + j0]);
        const float4 wa = *reinterpret_cast<const float4*>(&sW[dl * HP + h0]);
        const float4 wb = *reinterpret_cast<const float4*>(&sW[dl * HP + h0 + 4]);
        fma_tile(acc, xv, wa, wb);
      }
    }
    __syncthreads();
  }
  if (active) {
#pragma unroll
    for (int jj = 0; jj < 4; ++jj) {
      const int r = r0 + j0 + jj;
      if (r >= P) continue;
      float o[8];
#pragma unroll
      for (int hh = 0; hh < 8; ++hh) {
        const int h = h0 + hh;
        float v = 0.f;
        if (h < Hh) {
          v = acc[jj][hh];
          if (part == 0) v += b1[h];
        }
        o[hh] = v;
      }
      float4* dst = reinterpret_cast<float4*>(&outp[(size_t)r * HP + h0]);
      dst[0] = make_float4(o[0], o[1], o[2], o[3]);
      dst[1] = make_float4(o[4], o[5], o[6], o[7]);
    }
  }
}

// ------------- kernel 2: per-i block -> bilinear GEMM + fused MLP -------------
__global__ __launch_bounds__(256) void k_main(
    const float* __restrict__ G, const float* __restrict__ W1,
    const float* __restrict__ W2, const float* __restrict__ b2,
    const float* __restrict__ W3, const float* __restrict__ b3,
    const float* __restrict__ A, const float* __restrict__ B,
    float* __restrict__ out, int P, int K) {
  const int i = blockIdx.x;
  const int jcount = min(i, K);
  if (jcount == 0) return;
  const int jstart = i - jcount;
  const int base = (i <= K) ? i * (i - 1) / 2 : K * (K - 1) / 2 + (i - K) * K;

  __shared__ __align__(16) float arena[ARENA];
  float* gi  = arena;
  float* Xt  = arena + XT_OFF;
  float* Wc  = arena + WC_OFF;
  float* H1t = arena;            // phase 2 (reuses phase-1 space)
  float* Wc2 = arena + WC2_OFF;
  float* red = arena;            // phase 3 [NHG][JP]

  const int tid = threadIdx.x;
  for (int t = tid; t < Dd; t += 256) gi[t] = G[(size_t)i * Dd + t];
  __syncthreads();

  const int jg = tid % NJG, hg = tid / NJG;
  const bool active = hg < NHG;
  const int j0 = jg * 4, h0 = hg * 8;
  const float* W1c = W1 + (size_t)2 * Dd * Hh;

  // ---- layer 1 bilinear: acc[j][h] = sum_d (gi[d]*gj[d]) * W1c[d][h] ----
  float acc[4][8] = {};
  for (int c = 0; c < NCH; ++c) {
    const int d0 = c * DC;
    for (int t = tid; t < DC * HP; t += 256) {
      const int dl = t / HP, h = t - dl * HP;
      const int d = d0 + dl;
      Wc[t] = (h < Hh && d < Dd) ? W1c[(size_t)d * Hh + h] : 0.f;
    }
    for (int t = tid; t < JP * DC; t += 256) {
      const int j = t >> 6, dl = t & (DC - 1);
      const int d = d0 + dl;
      float v = 0.f;
      if (j < jcount && d < Dd) v = gi[d] * G[(size_t)(jstart + j) * Dd + d];
      Xt[dl * JP + j] = v;
    }
    __syncthreads();
    if (active) {
#pragma unroll 4
      for (int dl = 0; dl < DC; ++dl) {
        const float4 xv = *reinterpret_cast<const float4*>(&Xt[dl * JP + j0]);
        const float4 wa = *reinterpret_cast<const float4*>(&Wc[dl * HP + h0]);
        const float4 wb = *reinterpret_cast<const float4*>(&Wc[dl * HP + h0 + 4]);
        fma_tile(acc, xv, wa, wb);
      }
    }
    __syncthreads();
  }

  // ---- h1 = relu(acc + A[i,h] + B[j,h]); store transposed H1t[h][j] ----
  if (active) {
    const float4 a0 = *reinterpret_cast<const float4*>(&A[(size_t)i * HP + h0]);
    const float4 a1 = *reinterpret_cast<const float4*>(&A[(size_t)i * HP + h0 + 4]);
    const float av[8] = {a0.x, a0.y, a0.z, a0.w, a1.x, a1.y, a1.z, a1.w};
#pragma unroll
    for (int jj = 0; jj < 4; ++jj) {
      const int j = j0 + jj;
      float hv[8];
      if (j < jcount) {
        const size_t brow = (size_t)(jstart + j) * HP;
        const float4 bb0 = *reinterpret_cast<const float4*>(&B[brow + h0]);
        const float4 bb1 = *reinterpret_cast<const float4*>(&B[brow + h0 + 4]);
        const float bv[8] = {bb0.x, bb0.y, bb0.z, bb0.w, bb1.x, bb1.y, bb1.z, bb1.w};
#pragma unroll
        for (int hh = 0; hh < 8; ++hh)
          hv[hh] = fmaxf(acc[jj][hh] + av[hh] + bv[hh], 0.f);
      } else {
#pragma unroll
        for (int hh = 0; hh < 8; ++hh) hv[hh] = 0.f;
      }
#pragma unroll
      for (int hh = 0; hh < 8; ++hh) H1t[(h0 + hh) * JP + j] = hv[hh];
    }
  }

  // ---- layer 2: acc2[j][h2] = sum_h1 H1t[h1][j] * W2[h1][h2] ----
  float acc2[4][8] = {};
  for (int c = 0; c < NCH2; ++c) {
    const int d0 = c * DC2;
    const int dn = min(DC2, HP - d0);
    for (int t = tid; t < DC2 * HP; t += 256) {
      const int dl = t / HP, h = t - dl * HP;
      const int d = d0 + dl;
      Wc2[t] = (h < Hh && d < Hh) ? W2[(size_t)d * Hh + h] : 0.f;
    }
    __syncthreads();
    if (active) {
#pragma unroll 4
      for (int dl = 0; dl < dn; ++dl) {
        const int d = d0 + dl;
        const float4 xv = *reinterpret_cast<const float4*>(&H1t[d * JP + j0]);
        const float4 wa = *reinterpret_cast<const float4*>(&Wc2[dl * HP + h0]);
        const float4 wb = *reinterpret_cast<const float4*>(&Wc2[dl * HP + h0 + 4]);
        fma_tile(acc2, xv, wa, wb);
      }
    }
    __syncthreads();
  }

  // ---- layer 3: out[j] = sum_h2 relu(acc2 + b2) * W3[h2] + b3 ----
  float pacc[4] = {0.f, 0.f, 0.f, 0.f};
  if (active) {
    float w3v[8], b2v[8];
#pragma unroll
    for (int hh = 0; hh < 8; ++hh) {
      const int h = h0 + hh;
      w3v[hh] = (h < Hh) ? W3[h] : 0.f;
      b2v[hh] = (h < Hh) ? b2[h] : 0.f;
    }
#pragma unroll
    for (int jj = 0; jj < 4; ++jj) {
      float s = 0.f;
#pragma unroll
      for (int hh = 0; hh < 8; ++hh)
        s += fmaxf(acc2[jj][hh] + b2v[hh], 0.f) * w3v[hh];
      pacc[jj] = s;
    }
  }
  __syncthreads();  // all H1t/Wc2 reads retired; arena reusable for reduction
  if (active) {
#pragma unroll
    for (int jj = 0; jj < 4; ++jj) red[hg * JP + j0 + jj] = pacc[jj];
  }
  __syncthreads();
  if (tid < jcount) {
    float s = 0.f;
    for (int g = 0; g < NHG; ++g) s += red[g * JP + tid];  // deterministic order
    out[base + tid] = s + b3[0];
  }
}

extern "C" void kernel_launch(void* const* d_in, const int* in_sizes, int n_in,
                              void* d_out, int out_size, void* d_ws, size_t ws_size,
                              hipStream_t stream) {
  const float* M    = (const float*)d_in[0];
  const int*   pidx = (const int*)d_in[1];
  // d_in[2] = K (device scalar; K derived host-side from out_size instead)
  const float* W1   = (const float*)d_in[3];
  const float* b1   = (const float*)d_in[4];
  const float* W2   = (const float*)d_in[5];
  const float* b2   = (const float*)d_in[6];
  const float* W3   = (const float*)d_in[7];
  const float* b3   = (const float*)d_in[8];
  float* out = (float*)d_out;

  const int P = in_sizes[1];  // 2000
  int K = 50;
  for (int k = 1; k <= P; ++k) {
    const long long np = (long long)k * (k - 1) / 2 + (long long)(P - k) * k;
    if (np == (long long)out_size) { K = k; break; }
  }

  // ws: G [P][1200] | A [P][152] | B [P][152]  = 12.0 MB
  float* G = (float*)d_ws;
  float* A = G + (size_t)P * Dd;
  float* B = A + (size_t)P * HP;

  k_gather<<<P, 256, 0, stream>>>(M, pidx, G);
  dim3 gp((P + JP - 1) / JP, 2);
  k_precomp<<<gp, 256, 0, stream>>>(G, W1, b1, A, P);
  k_main<<<P, 256, 0, stream>>>(G, W1, W2, b2, W3, b3, A, B, out, P, K);
}

// Round 2
// 371.294 us; speedup vs baseline: 4.2412x; 4.2412x over previous
//
#include <hip/hip_runtime.h>

// PairwiseScore via pair-flattened MFMA GEMM (bf16x3 split precision).
// h1pre[r] = gi*W1a (A, precomp) + gj*W1b (B, precomp) + (gi.gj)@W1c (pair GEMM) + b1
// h2 = relu(h1 @ W2 + b2);  out = h2 @ W3 + b3
// Fixed shapes: M=10000, D=1200(->1216), P=2000, K=50, H=150(->160), NP=98725.

typedef __attribute__((ext_vector_type(8))) short short8;
typedef __attribute__((ext_vector_type(4))) float f32x4;

constexpr int DP   = 1216;       // padded G_DIM (38*32)
constexpr int HPAD = 160;        // padded hidden
constexpr int NKC  = 38;         // K-chunks of 32 over DP
constexpr int NKC2 = 5;          // K-chunks over HPAD
constexpr int ROWS = 128;        // pair rows per block
constexpr int WCH  = 2 * HPAD * 32;  // ushorts per staged W chunk (hi+lo) = 10240

__device__ __forceinline__ ushort bf16_rne(float x) {
  uint u = __float_as_uint(x);
  u += 0x7FFFu + ((u >> 16) & 1u);
  return (ushort)(u >> 16);
}
__device__ __forceinline__ float bf16f(ushort h) {
  return __uint_as_float((uint)h << 16);
}
__device__ __forceinline__ f32x4 mfma16(short8 a, short8 b, f32x4 c) {
  return __builtin_amdgcn_mfma_f32_16x16x32_bf16(a, b, c, 0, 0, 0);
}

// ---------- kernel: split/transpose/pad weights into chunk-major bf16 hi/lo ----------
// W1ch[slab][c][2][160][32], W2ch[c][2][160][32]   (element [hl][col][kk], k = c*32+kk)
__global__ void k_prep(const float* __restrict__ W1, const float* __restrict__ W2,
                       ushort* __restrict__ W1ch, ushort* __restrict__ W2ch) {
  int idx = blockIdx.x * 256 + threadIdx.x;
  const int C1 = NKC * HPAD * 32;  // 194560 per slab
  if (idx < 3 * C1) {
    int slab = idx / C1, rem = idx % C1;
    int c = rem / (HPAD * 32), rem2 = rem % (HPAD * 32);
    int col = rem2 >> 5, kk = rem2 & 31;
    int k = c * 32 + kk;
    float v = (k < 1200 && col < 150) ? W1[((size_t)slab * 1200 + k) * 150 + col] : 0.f;
    ushort h = bf16_rne(v);
    ushort l = bf16_rne(v - bf16f(h));
    size_t base = (size_t)(slab * NKC + c) * WCH + (size_t)col * 32 + kk;
    W1ch[base] = h;
    W1ch[base + HPAD * 32] = l;
  } else {
    idx -= 3 * C1;
    if (idx < NKC2 * HPAD * 32) {
      int c = idx / (HPAD * 32), rem2 = idx % (HPAD * 32);
      int col = rem2 >> 5, kk = rem2 & 31;
      int k = c * 32 + kk;
      float v = (k < 150 && col < 150) ? W2[(size_t)k * 150 + col] : 0.f;
      ushort h = bf16_rne(v);
      ushort l = bf16_rne(v - bf16f(h));
      size_t base = (size_t)c * WCH + (size_t)col * 32 + kk;
      W2ch[base] = h;
      W2ch[base + HPAD * 32] = l;
    }
  }
}

// ---------- kernel: gather G = mention_reprs[pruned_idx], pad 1200->1216 ----------
__global__ void k_gather(const float* __restrict__ M, const int* __restrict__ pidx,
                         float* __restrict__ G) {
  const int i = blockIdx.x;
  const int r = pidx[i];
  const float4* src = reinterpret_cast<const float4*>(M + (size_t)r * 1200);
  float4* dst = reinterpret_cast<float4*>(G + (size_t)i * DP);
  for (int t = threadIdx.x; t < DP / 4; t += blockDim.x)
    dst[t] = (t < 300) ? src[t] : make_float4(0.f, 0.f, 0.f, 0.f);
}

// ---------- kernel: AB[slab][r][col] = G[r,:] @ W1slab (+b1 if slab 0), bf16x3 ----------
__global__ __launch_bounds__(256, 2) void k_precomp(
    const float* __restrict__ G, const ushort* __restrict__ W1ch,
    const float* __restrict__ b1, float* __restrict__ AB, int P) {
  __shared__ __align__(16) char smem[16384 + 20480 + 640];
  ushort* Xbuf = (ushort*)smem;                 // [2][128][32]
  ushort* Wbuf = (ushort*)(smem + 16384);       // [2][160][32]
  float* b1f = (float*)(smem + 36864);

  const int tid = threadIdx.x;
  const int lane = tid & 63, wv = tid >> 6;
  const int l15 = lane & 15, kb = lane >> 4;
  const int wrow0 = wv * 32;
  const int r0 = blockIdx.x * ROWS;
  const int slab = blockIdx.y;

  if (tid < HPAD) b1f[tid] = (slab == 0 && tid < 150) ? b1[tid] : 0.f;

  const int srow = tid >> 1, shalf = tid & 1;
  const bool rv = (r0 + srow) < P;
  const int grow = min(r0 + srow, P - 1);
  const float* ps = G + (size_t)grow * DP + shalf * 16;
  uint* xdh = (uint*)&Xbuf[srow * 32 + shalf * 16];
  uint* xdl = (uint*)&Xbuf[ROWS * 32 + srow * 32 + shalf * 16];
  const ushort* wsrc = W1ch + (size_t)(slab * NKC) * WCH;

  f32x4 acc[2][10];
#pragma unroll
  for (int a = 0; a < 2; ++a)
#pragma unroll
    for (int b = 0; b < 10; ++b) acc[a][b] = (f32x4)(0.f);

  for (int c = 0; c < NKC; ++c) {
    if (c) __syncthreads();
    {  // stage X = split(G rows)
      const float4* g4 = (const float4*)(ps + (size_t)c * 32);
      uint hw[8], lw[8];
#pragma unroll
      for (int s = 0; s < 4; ++s) {
        float4 a = rv ? g4[s] : make_float4(0.f, 0.f, 0.f, 0.f);
        float p[4] = {a.x, a.y, a.z, a.w};
#pragma unroll
        for (int e = 0; e < 2; ++e) {
          ushort h0 = bf16_rne(p[2 * e]), h1 = bf16_rne(p[2 * e + 1]);
          ushort l0 = bf16_rne(p[2 * e] - bf16f(h0));
          ushort l1 = bf16_rne(p[2 * e + 1] - bf16f(h1));
          hw[s * 2 + e] = (uint)h0 | ((uint)h1 << 16);
          lw[s * 2 + e] = (uint)l0 | ((uint)l1 << 16);
        }
      }
      ((uint4*)xdh)[0] = make_uint4(hw[0], hw[1], hw[2], hw[3]);
      ((uint4*)xdh)[1] = make_uint4(hw[4], hw[5], hw[6], hw[7]);
      ((uint4*)xdl)[0] = make_uint4(lw[0], lw[1], lw[2], lw[3]);
      ((uint4*)xdl)[1] = make_uint4(lw[4], lw[5], lw[6], lw[7]);
    }
    {  // stage W chunk (contiguous copy)
      const uint4* src = (const uint4*)(wsrc + (size_t)c * WCH);
      uint4* dst = (uint4*)Wbuf;
      for (int o = tid; o < WCH / 8; o += 256) dst[o] = src[o];
    }
    __syncthreads();
    short8 ah[2], al[2];
#pragma unroll
    for (int rt = 0; rt < 2; ++rt) {
      const int rr = wrow0 + rt * 16 + l15;
      ah[rt] = *(const short8*)&Xbuf[rr * 32 + kb * 8];
      al[rt] = *(const short8*)&Xbuf[ROWS * 32 + rr * 32 + kb * 8];
    }
#pragma unroll
    for (int ct = 0; ct < 10; ++ct) {
      const short8 bh = *(const short8*)&Wbuf[(ct * 16 + l15) * 32 + kb * 8];
      const short8 bl = *(const short8*)&Wbuf[(HPAD + ct * 16 + l15) * 32 + kb * 8];
#pragma unroll
      for (int rt = 0; rt < 2; ++rt) {
        acc[rt][ct] = mfma16(ah[rt], bh, acc[rt][ct]);
        acc[rt][ct] = mfma16(al[rt], bh, acc[rt][ct]);
        acc[rt][ct] = mfma16(ah[rt], bl, acc[rt][ct]);
      }
    }
  }
  // epilogue: AB[slab][r][col] = acc + b1f
#pragma unroll
  for (int rt = 0; rt < 2; ++rt) {
#pragma unroll
    for (int q = 0; q < 4; ++q) {
      const int rr = wrow0 + rt * 16 + kb * 4 + q;
      const int gr = r0 + rr;
      if (gr < P) {
#pragma unroll
        for (int ct = 0; ct < 10; ++ct) {
          const int col = ct * 16 + l15;
          AB[((size_t)slab * P + gr) * HPAD + col] = acc[rt][ct][q] + b1f[col];
        }
      }
    }
  }
}

// ---------- kernel: main pair GEMM + fused MLP ----------
__global__ __launch_bounds__(256, 2) void k_main(
    const float* __restrict__ G, const ushort* __restrict__ W1ch,
    const ushort* __restrict__ W2ch, const float* __restrict__ AB,
    const float* __restrict__ b2, const float* __restrict__ W3,
    const float* __restrict__ b3, float* __restrict__ out,
    int P, int K, int NP) {
  __shared__ __align__(16) char smem[63744];
  ushort* Xbuf = (ushort*)smem;                  // phase A: [2][128][32]  (16384B)
  ushort* Wbuf = (ushort*)(smem + 16384);        // phase A: [2][160][32]  (20480B)
  ushort* H1 = (ushort*)smem;                    // phase B: [128][160]    (40960B)
  ushort* W2buf = (ushort*)(smem + 40960);       // phase B: [2][160][32]  (20480B)
  int* pI = (int*)(smem + 61440);
  int* pJ = (int*)(smem + 61952);
  float* b2f = (float*)(smem + 62464);
  float* W3f = (float*)(smem + 63104);

  const int tid = threadIdx.x;
  const int lane = tid & 63, wv = tid >> 6;
  const int l15 = lane & 15, kb = lane >> 4;
  const int wrow0 = wv * 32;
  const int r0 = blockIdx.x * ROWS;

  if (tid < HPAD) {
    b2f[tid] = (tid < 150) ? b2[tid] : 0.f;
    W3f[tid] = (tid < 150) ? W3[tid] : 0.f;
  }
  if (tid < ROWS) {  // pair table: global pair r -> (i, j)
    const int r = r0 + tid;
    int i, j;
    if (r >= NP) { i = 1; j = 0; }
    else {
      const int T = K * (K - 1) / 2;
      if (r < T) {
        int ii = (int)((1.0f + sqrtf(1.0f + 8.0f * (float)r)) * 0.5f);
        while (ii * (ii - 1) / 2 > r) --ii;
        while ((ii + 1) * ii / 2 <= r) ++ii;
        i = ii; j = r - ii * (ii - 1) / 2;
      } else {
        const int rp = r - T, q = rp / K;
        i = K + q; j = i - K + (rp - q * K);
      }
    }
    pI[tid] = i; pJ[tid] = j;
  }
  __syncthreads();

  const int srow = tid >> 1, shalf = tid & 1;
  const float* pgi = G + (size_t)pI[srow] * DP + shalf * 16;
  const float* pgj = G + (size_t)pJ[srow] * DP + shalf * 16;
  uint* xdh = (uint*)&Xbuf[srow * 32 + shalf * 16];
  uint* xdl = (uint*)&Xbuf[ROWS * 32 + srow * 32 + shalf * 16];
  const ushort* wsrc = W1ch + (size_t)(2 * NKC) * WCH;  // slab 2 = W1c

  f32x4 acc[2][10];
#pragma unroll
  for (int a = 0; a < 2; ++a)
#pragma unroll
    for (int b = 0; b < 10; ++b) acc[a][b] = (f32x4)(0.f);

  // ---- layer 1 bilinear: (gi.gj) @ W1c, bf16x3 ----
  for (int c = 0; c < NKC; ++c) {
    if (c) __syncthreads();
    {  // stage X = split(gi*gj)
      const float4* gi4 = (const float4*)(pgi + (size_t)c * 32);
      const float4* gj4 = (const float4*)(pgj + (size_t)c * 32);
      uint hw[8], lw[8];
#pragma unroll
      for (int s = 0; s < 4; ++s) {
        const float4 a = gi4[s], b = gj4[s];
        float p[4] = {a.x * b.x, a.y * b.y, a.z * b.z, a.w * b.w};
#pragma unroll
        for (int e = 0; e < 2; ++e) {
          ushort h0 = bf16_rne(p[2 * e]), h1 = bf16_rne(p[2 * e + 1]);
          ushort l0 = bf16_rne(p[2 * e] - bf16f(h0));
          ushort l1 = bf16_rne(p[2 * e + 1] - bf16f(h1));
          hw[s * 2 + e] = (uint)h0 | ((uint)h1 << 16);
          lw[s * 2 + e] = (uint)l0 | ((uint)l1 << 16);
        }
      }
      ((uint4*)xdh)[0] = make_uint4(hw[0], hw[1], hw[2], hw[3]);
      ((uint4*)xdh)[1] = make_uint4(hw[4], hw[5], hw[6], hw[7]);
      ((uint4*)xdl)[0] = make_uint4(lw[0], lw[1], lw[2], lw[3]);
      ((uint4*)xdl)[1] = make_uint4(lw[4], lw[5], lw[6], lw[7]);
    }
    {  // stage W chunk
      const uint4* src = (const uint4*)(wsrc + (size_t)c * WCH);
      uint4* dst = (uint4*)Wbuf;
      for (int o = tid; o < WCH / 8; o += 256) dst[o] = src[o];
    }
    __syncthreads();
    short8 ah[2], al[2];
#pragma unroll
    for (int rt = 0; rt < 2; ++rt) {
      const int rr = wrow0 + rt * 16 + l15;
      ah[rt] = *(const short8*)&Xbuf[rr * 32 + kb * 8];
      al[rt] = *(const short8*)&Xbuf[ROWS * 32 + rr * 32 + kb * 8];
    }
#pragma unroll
    for (int ct = 0; ct < 10; ++ct) {
      const short8 bh = *(const short8*)&Wbuf[(ct * 16 + l15) * 32 + kb * 8];
      const short8 bl = *(const short8*)&Wbuf[(HPAD + ct * 16 + l15) * 32 + kb * 8];
#pragma unroll
      for (int rt = 0; rt < 2; ++rt) {
        acc[rt][ct] = mfma16(ah[rt], bh, acc[rt][ct]);
        acc[rt][ct] = mfma16(al[rt], bh, acc[rt][ct]);
        acc[rt][ct] = mfma16(ah[rt], bl, acc[rt][ct]);
      }
    }
  }
  __syncthreads();  // phase A reads done; H1 may overwrite X/W regions

  // ---- h1 = relu(acc + A[i] + B[j]) -> H1 bf16 [row][160] ----
#pragma unroll
  for (int rt = 0; rt < 2; ++rt) {
#pragma unroll
    for (int q = 0; q < 4; ++q) {
      const int rr = wrow0 + rt * 16 + kb * 4 + q;
      const float* Ar = AB + (size_t)pI[rr] * HPAD;
      const float* Br = AB + ((size_t)P + pJ[rr]) * HPAD;
#pragma unroll
      for (int ct = 0; ct < 10; ++ct) {
        const int col = ct * 16 + l15;
        const float v = acc[rt][ct][q] + Ar[col] + Br[col];
        H1[rr * HPAD + col] = bf16_rne(fmaxf(v, 0.f));
      }
    }
  }

  // ---- layer 2: H1 @ W2 (H1 bf16, W2 split -> 2 terms) ----
  f32x4 acc2[2][10];
#pragma unroll
  for (int a = 0; a < 2; ++a)
#pragma unroll
    for (int b = 0; b < 10; ++b) acc2[a][b] = (f32x4)(0.f);

  for (int c2 = 0; c2 < NKC2; ++c2) {
    __syncthreads();
    {
      const uint4* src = (const uint4*)(W2ch + (size_t)c2 * WCH);
      uint4* dst = (uint4*)W2buf;
      for (int o = tid; o < WCH / 8; o += 256) dst[o] = src[o];
    }
    __syncthreads();
    short8 a2[2];
#pragma unroll
    for (int rt = 0; rt < 2; ++rt) {
      const int rr = wrow0 + rt * 16 + l15;
      a2[rt] = *(const short8*)&H1[rr * HPAD + c2 * 32 + kb * 8];
    }
#pragma unroll
    for (int ct = 0; ct < 10; ++ct) {
      const short8 bh = *(const short8*)&W2buf[(ct * 16 + l15) * 32 + kb * 8];
      const short8 bl = *(const short8*)&W2buf[(HPAD + ct * 16 + l15) * 32 + kb * 8];
#pragma unroll
      for (int rt = 0; rt < 2; ++rt) {
        acc2[rt][ct] = mfma16(a2[rt], bh, acc2[rt][ct]);
        acc2[rt][ct] = mfma16(a2[rt], bl, acc2[rt][ct]);
      }
    }
  }

  // ---- layer 3: out[r] = sum_h relu(acc2 + b2) * W3 + b3 ----
  const float b3v = b3[0];
#pragma unroll
  for (int rt = 0; rt < 2; ++rt) {
#pragma unroll
    for (int q = 0; q < 4; ++q) {
      float s = 0.f;
#pragma unroll
      for (int ct = 0; ct < 10; ++ct) {
        const int col = ct * 16 + l15;
        const float h2 = fmaxf(acc2[rt][ct][q] + b2f[col], 0.f);
        s = fmaf(h2, W3f[col], s);
      }
#pragma unroll
      for (int off = 1; off < 16; off <<= 1) s += __shfl_xor(s, off, 16);
      if (l15 == 0) {
        const int gr = r0 + wrow0 + rt * 16 + kb * 4 + q;
        if (gr < NP) out[gr] = s + b3v;
      }
    }
  }
}

extern "C" void kernel_launch(void* const* d_in, const int* in_sizes, int n_in,
                              void* d_out, int out_size, void* d_ws, size_t ws_size,
                              hipStream_t stream) {
  const float* M    = (const float*)d_in[0];
  const int*   pidx = (const int*)d_in[1];
  const float* W1   = (const float*)d_in[3];
  const float* b1   = (const float*)d_in[4];
  const float* W2   = (const float*)d_in[5];
  const float* b2   = (const float*)d_in[6];
  const float* W3   = (const float*)d_in[7];
  const float* b3   = (const float*)d_in[8];
  float* out = (float*)d_out;

  const int P = in_sizes[1];
  const int NP = out_size;
  int K = 50;
  for (int k = 1; k <= P; ++k) {
    const long long np = (long long)k * (k - 1) / 2 + (long long)(P - k) * k;
    if (np == (long long)NP) { K = k; break; }
  }

  // ws layout: G [P][1216] f32 | AB [2][P][160] f32 | W1ch [3][38][2][160][32] bf16 | W2ch [5][2][160][32] bf16
  float* G = (float*)d_ws;
  float* AB = G + (size_t)P * DP;
  ushort* W1ch = (ushort*)(AB + (size_t)2 * P * HPAD);
  ushort* W2ch = W1ch + (size_t)3 * NKC * WCH;

  const int prepN = 3 * NKC * HPAD * 32 + NKC2 * HPAD * 32;
  k_prep<<<(prepN + 255) / 256, 256, 0, stream>>>(W1, W2, W1ch, W2ch);
  k_gather<<<P, 256, 0, stream>>>(M, pidx, G);
  dim3 gp((P + ROWS - 1) / ROWS, 2);
  k_precomp<<<gp, 256, 0, stream>>>(G, W1ch, b1, AB, P);
  const int nb = (NP + ROWS - 1) / ROWS;
  k_main<<<nb, 256, 0, stream>>>(G, W1ch, W2ch, AB, b2, W3, b3, out, P, K, NP);
}

// Round 3
// 252.620 us; speedup vs baseline: 6.2335x; 1.4698x over previous
//
#include <hip/hip_runtime.h>

// PairwiseScore, round 3: MFMA pair-GEMM with register A-fragments,
// swizzled global_load_lds W staging (1 barrier/chunk), split L2/L3 kernel.
//   h1 = relu(gi@W1a + gj@W1b + (gi.gj)@W1c + b1)   [A/B precomp per mention]
//   out = relu(h1@W2 + b2) @ W3 + b3
// Shapes: M=10000, D=1200(->1216), P=2000, K=50, H=150(->160), NP=98725.
// ws needed: G 9.73MB + AB 2.56MB + W1ch 2.33MB + W2ch 0.1MB + H1 31.6MB = 46.4MB

typedef __attribute__((ext_vector_type(8))) short short8;
typedef __attribute__((ext_vector_type(4))) float f32x4;

constexpr int DP    = 1216;      // padded G_DIM (38*32)
constexpr int HPAD  = 160;       // padded hidden
constexpr int NKC   = 38;        // K-chunks of 32 over DP
constexpr int NKC2  = 5;         // K-chunks of 32 over HPAD
constexpr int ROWS  = 128;       // pair rows per block
constexpr int WCHU  = 10240;     // ushorts per W chunk image (hi 5120 + lo 5120)

__device__ __forceinline__ ushort bf16_rne(float x) {
  uint u = __float_as_uint(x);
  u += 0x7FFFu + ((u >> 16) & 1u);
  return (ushort)(u >> 16);
}
__device__ __forceinline__ float bf16f(ushort h) {
  return __uint_as_float((uint)h << 16);
}
__device__ __forceinline__ f32x4 mfma16(short8 a, short8 b, f32x4 c) {
  return __builtin_amdgcn_mfma_f32_16x16x32_bf16(a, b, c, 0, 0, 0);
}
__device__ __forceinline__ void g2lds16(const void* g, void* l) {
  __builtin_amdgcn_global_load_lds(
      (const __attribute__((address_space(1))) void*)g,
      (__attribute__((address_space(3))) void*)l, 16, 0, 0);
}
// stage one 20480B W-chunk image: 4 waves x 5 issues x 1024B (linear copy)
__device__ __forceinline__ void stage_chunk(const ushort* gsrc, ushort* lbuf,
                                            int w, int lane) {
  const char* g = (const char*)gsrc + w * 5120 + lane * 16;
  char* l = (char*)lbuf + w * 5120;
#pragma unroll
  for (int q = 0; q < 5; ++q) g2lds16(g + q * 1024, l + q * 1024);
}
// split product a[e]*b[e] (e=0..7) into bf16 hi (trunc) + lo (exact residual, trunc)
__device__ __forceinline__ void split8(const float* a, const float* b,
                                       short8& hi, short8& lo) {
  const float4 a0 = *(const float4*)a, a1 = *(const float4*)(a + 4);
  const float4 b0 = *(const float4*)b, b1 = *(const float4*)(b + 4);
  float p[8] = {a0.x * b0.x, a0.y * b0.y, a0.z * b0.z, a0.w * b0.w,
                a1.x * b1.x, a1.y * b1.y, a1.z * b1.z, a1.w * b1.w};
  uint h[4], l[4];
#pragma unroll
  for (int e = 0; e < 4; ++e) {
    uint u0 = __float_as_uint(p[2 * e]), u1 = __float_as_uint(p[2 * e + 1]);
    float r0 = p[2 * e] - __uint_as_float(u0 & 0xffff0000u);
    float r1 = p[2 * e + 1] - __uint_as_float(u1 & 0xffff0000u);
    h[e] = __builtin_amdgcn_perm(u1, u0, 0x07060302u);
    l[e] = __builtin_amdgcn_perm(__float_as_uint(r1), __float_as_uint(r0),
                                 0x07060302u);
  }
  uint4 hu = make_uint4(h[0], h[1], h[2], h[3]);
  uint4 lu = make_uint4(l[0], l[1], l[2], l[3]);
  hi = *(short8*)&hu; lo = *(short8*)&lu;
}
__device__ __forceinline__ void split8_one(const float* a, short8& hi, short8& lo) {
  const float4 a0 = *(const float4*)a, a1 = *(const float4*)(a + 4);
  float p[8] = {a0.x, a0.y, a0.z, a0.w, a1.x, a1.y, a1.z, a1.w};
  uint h[4], l[4];
#pragma unroll
  for (int e = 0; e < 4; ++e) {
    uint u0 = __float_as_uint(p[2 * e]), u1 = __float_as_uint(p[2 * e + 1]);
    float r0 = p[2 * e] - __uint_as_float(u0 & 0xffff0000u);
    float r1 = p[2 * e + 1] - __uint_as_float(u1 & 0xffff0000u);
    h[e] = __builtin_amdgcn_perm(u1, u0, 0x07060302u);
    l[e] = __builtin_amdgcn_perm(__float_as_uint(r1), __float_as_uint(r0),
                                 0x07060302u);
  }
  uint4 hu = make_uint4(h[0], h[1], h[2], h[3]);
  uint4 lu = make_uint4(l[0], l[1], l[2], l[3]);
  hi = *(short8*)&hu; lo = *(short8*)&lu;
}

// ---------- k_prep: W1/W2 -> chunk-major, bf16 hi/lo, XOR-swizzled image ----------
// chunk image (10240 ushort): slot((hl*160+col)*32+kk ^ ((col&7)<<3)) = W[k=c*32+kk][col]
__global__ void k_prep(const float* __restrict__ W1, const float* __restrict__ W2,
                       ushort* __restrict__ W1ch, ushort* __restrict__ W2ch) {
  const int N1 = 3 * NKC * HPAD * 32;
  int idx = blockIdx.x * 256 + threadIdx.x;
  if (idx < N1) {
    int s = idx / (NKC * HPAD * 32), r1 = idx % (NKC * HPAD * 32);
    int c = r1 / (HPAD * 32), r2 = r1 % (HPAD * 32);
    int col = r2 >> 5, kk = r2 & 31;
    int k = c * 32 + kk;
    float v = (k < 1200 && col < 150) ? W1[((size_t)s * 1200 + k) * 150 + col] : 0.f;
    ushort h = bf16_rne(v);
    ushort l = bf16_rne(v - bf16f(h));
    size_t base = (size_t)(s * NKC + c) * WCHU;
    int i0 = (col * 32 + kk) ^ ((col & 7) << 3);
    W1ch[base + i0] = h;
    W1ch[base + i0 + 5120] = l;
  } else {
    idx -= N1;
    if (idx < NKC2 * HPAD * 32) {
      int c = idx / (HPAD * 32), r2 = idx % (HPAD * 32);
      int col = r2 >> 5, kk = r2 & 31;
      int k = c * 32 + kk;
      float v = (k < 150 && col < 150) ? W2[(size_t)k * 150 + col] : 0.f;
      ushort h = bf16_rne(v);
      ushort l = bf16_rne(v - bf16f(h));
      size_t base = (size_t)c * WCHU;
      int i0 = (col * 32 + kk) ^ ((col & 7) << 3);
      W2ch[base + i0] = h;
      W2ch[base + i0 + 5120] = l;
    }
  }
}

// ---------- k_gather: G = mention_reprs[pruned_idx], pad 1200->1216 ----------
__global__ void k_gather(const float* __restrict__ M, const int* __restrict__ pidx,
                         float* __restrict__ G) {
  const int i = blockIdx.x;
  const int r = pidx[i];
  const float4* src = reinterpret_cast<const float4*>(M + (size_t)r * 1200);
  float4* dst = reinterpret_cast<float4*>(G + (size_t)i * DP);
  for (int t = threadIdx.x; t < DP / 4; t += blockDim.x)
    dst[t] = (t < 300) ? src[t] : make_float4(0.f, 0.f, 0.f, 0.f);
}

// ---------- k_precomp: AB[slab][r][col] = G[r]@W1slab (+b1 if slab0) ----------
__global__ __launch_bounds__(256, 3) void k_precomp(
    const float* __restrict__ G, const ushort* __restrict__ W1ch,
    const float* __restrict__ b1, float* __restrict__ AB, int P) {
  __shared__ __align__(16) ushort Wb0[WCHU];
  __shared__ __align__(16) ushort Wb1[WCHU];
  const int tid = threadIdx.x, lane = tid & 63, w = tid >> 6;
  const int l15 = lane & 15, kb = lane >> 4;
  const int r0 = blockIdx.x * ROWS;
  const int slab = blockIdx.y;
  const ushort* wsrc = W1ch + (size_t)slab * NKC * WCHU;

  const int row0 = min(r0 + w * 32 + l15, P - 1);
  const int row1 = min(r0 + w * 32 + 16 + l15, P - 1);
  const float* g0 = G + (size_t)row0 * DP + kb * 8;
  const float* g1 = G + (size_t)row1 * DP + kb * 8;
  const int lbase = (l15 * 32 + kb * 8) ^ ((l15 & 7) << 3);

  f32x4 acc[2][10];
#pragma unroll
  for (int a = 0; a < 2; ++a)
#pragma unroll
    for (int b = 0; b < 10; ++b) acc[a][b] = (f32x4)(0.f);

  stage_chunk(wsrc, Wb0, w, lane);
  short8 ah0, al0, ah1, al1;
  split8_one(g0, ah0, al0);
  split8_one(g1, ah1, al1);

#pragma unroll 2
  for (int c = 0; c < NKC; ++c) {
    __syncthreads();
    if (c < NKC - 1)
      stage_chunk(wsrc + (size_t)(c + 1) * WCHU, (c & 1) ? Wb0 : Wb1, w, lane);
    const ushort* wb = (c & 1) ? Wb1 : Wb0;
#pragma unroll
    for (int ct = 0; ct < 10; ++ct) {
      const short8 bh = *(const short8*)&wb[lbase + ct * 512];
      const short8 bl = *(const short8*)&wb[lbase + ct * 512 + 5120];
      acc[0][ct] = mfma16(ah0, bh, acc[0][ct]);
      acc[1][ct] = mfma16(ah1, bh, acc[1][ct]);
      acc[0][ct] = mfma16(al0, bh, acc[0][ct]);
      acc[1][ct] = mfma16(al1, bh, acc[1][ct]);
      acc[0][ct] = mfma16(ah0, bl, acc[0][ct]);
      acc[1][ct] = mfma16(ah1, bl, acc[1][ct]);
    }
    if (c < NKC - 1) {
      split8_one(g0 + (c + 1) * 32, ah0, al0);
      split8_one(g1 + (c + 1) * 32, ah1, al1);
    }
  }
  float* outp = AB + (size_t)slab * P * HPAD;
#pragma unroll
  for (int rt = 0; rt < 2; ++rt)
#pragma unroll
    for (int q = 0; q < 4; ++q) {
      const int r = r0 + w * 32 + rt * 16 + kb * 4 + q;
      if (r < P) {
#pragma unroll
        for (int ct = 0; ct < 10; ++ct) {
          const int col = ct * 16 + l15;
          float v = acc[rt][ct][q];
          if (slab == 0 && col < 150) v += b1[col];
          outp[(size_t)r * HPAD + col] = v;
        }
      }
    }
}

// ---------- k_pair_l1: bilinear pair GEMM -> H1 bf16 [NPpad][160] ----------
__global__ __launch_bounds__(256, 3) void k_pair_l1(
    const float* __restrict__ G, const ushort* __restrict__ W1ch,
    const float* __restrict__ AB, ushort* __restrict__ H1,
    int P, int K, int NP) {
  __shared__ __align__(16) ushort Wb0[WCHU];
  __shared__ __align__(16) ushort Wb1[WCHU];
  __shared__ int pI[ROWS], pJ[ROWS];

  const int tid = threadIdx.x, lane = tid & 63, w = tid >> 6;
  const int l15 = lane & 15, kb = lane >> 4;
  const int r0 = blockIdx.x * ROWS;

  if (tid < ROWS) {  // pair table: global pair r -> (i, j)
    const int r = r0 + tid;
    int i, j;
    if (r >= NP) { i = 1; j = 0; }
    else {
      const int T = K * (K - 1) / 2;
      if (r < T) {
        int ii = (int)((1.0f + sqrtf(1.0f + 8.0f * (float)r)) * 0.5f);
        while (ii * (ii - 1) / 2 > r) --ii;
        while ((ii + 1) * ii / 2 <= r) ++ii;
        i = ii; j = r - ii * (ii - 1) / 2;
      } else {
        const int rp = r - T, q = rp / K;
        i = K + q; j = i - K + (rp - q * K);
      }
    }
    pI[tid] = i; pJ[tid] = j;
  }
  const ushort* wsrc = W1ch + (size_t)2 * NKC * WCHU;  // slab 2 = W1c
  stage_chunk(wsrc, Wb0, w, lane);
  __syncthreads();

  const int rowA = w * 32 + l15, rowB = w * 32 + 16 + l15;
  const float* gi0 = G + (size_t)pI[rowA] * DP + kb * 8;
  const float* gj0 = G + (size_t)pJ[rowA] * DP + kb * 8;
  const float* gi1 = G + (size_t)pI[rowB] * DP + kb * 8;
  const float* gj1 = G + (size_t)pJ[rowB] * DP + kb * 8;
  const int lbase = (l15 * 32 + kb * 8) ^ ((l15 & 7) << 3);

  f32x4 acc[2][10];
#pragma unroll
  for (int a = 0; a < 2; ++a)
#pragma unroll
    for (int b = 0; b < 10; ++b) acc[a][b] = (f32x4)(0.f);

  short8 ah0, al0, ah1, al1;
  split8(gi0, gj0, ah0, al0);
  split8(gi1, gj1, ah1, al1);

#pragma unroll 2
  for (int c = 0; c < NKC; ++c) {
    if (c) __syncthreads();
    if (c < NKC - 1)
      stage_chunk(wsrc + (size_t)(c + 1) * WCHU, (c & 1) ? Wb0 : Wb1, w, lane);
    const ushort* wb = (c & 1) ? Wb1 : Wb0;
#pragma unroll
    for (int ct = 0; ct < 10; ++ct) {
      const short8 bh = *(const short8*)&wb[lbase + ct * 512];
      const short8 bl = *(const short8*)&wb[lbase + ct * 512 + 5120];
      acc[0][ct] = mfma16(ah0, bh, acc[0][ct]);
      acc[1][ct] = mfma16(ah1, bh, acc[1][ct]);
      acc[0][ct] = mfma16(al0, bh, acc[0][ct]);
      acc[1][ct] = mfma16(al1, bh, acc[1][ct]);
      acc[0][ct] = mfma16(ah0, bl, acc[0][ct]);
      acc[1][ct] = mfma16(ah1, bl, acc[1][ct]);
    }
    if (c < NKC - 1) {
      split8(gi0 + (c + 1) * 32, gj0 + (c + 1) * 32, ah0, al0);
      split8(gi1 + (c + 1) * 32, gj1 + (c + 1) * 32, ah1, al1);
    }
  }
  // epilogue: h1 = relu(acc + A[i] + B[j]) -> H1 bf16 (pad rows written, pad cols 0)
#pragma unroll
  for (int rt = 0; rt < 2; ++rt)
#pragma unroll
    for (int q = 0; q < 4; ++q) {
      const int rr = w * 32 + rt * 16 + kb * 4 + q;
      const float* Ar = AB + (size_t)pI[rr] * HPAD;
      const float* Br = AB + ((size_t)P + pJ[rr]) * HPAD;
      ushort* hrow = H1 + (size_t)(r0 + rr) * HPAD;
#pragma unroll
      for (int ct = 0; ct < 10; ++ct) {
        const int col = ct * 16 + l15;
        const float v = acc[rt][ct][q] + Ar[col] + Br[col];
        hrow[col] = bf16_rne(fmaxf(v, 0.f));
      }
    }
}

// ---------- k_mlp: out = relu(H1@W2 + b2) @ W3 + b3 ----------
__global__ __launch_bounds__(256, 3) void k_mlp(
    const ushort* __restrict__ H1, const ushort* __restrict__ W2ch,
    const float* __restrict__ b2, const float* __restrict__ W3,
    const float* __restrict__ b3, float* __restrict__ out, int NP) {
  __shared__ __align__(16) ushort Wb0[WCHU];
  __shared__ __align__(16) ushort Wb1[WCHU];
  __shared__ float b2f[HPAD], W3f[HPAD];

  const int tid = threadIdx.x, lane = tid & 63, w = tid >> 6;
  const int l15 = lane & 15, kb = lane >> 4;
  const int r0 = blockIdx.x * ROWS;

  if (tid < HPAD) {
    b2f[tid] = (tid < 150) ? b2[tid] : 0.f;
    W3f[tid] = (tid < 150) ? W3[tid] : 0.f;
  }
  const ushort* h0 = H1 + (size_t)(r0 + w * 32 + l15) * HPAD + kb * 8;
  const ushort* h1 = H1 + (size_t)(r0 + w * 32 + 16 + l15) * HPAD + kb * 8;
  const int lbase = (l15 * 32 + kb * 8) ^ ((l15 & 7) << 3);

  f32x4 acc[2][10];
#pragma unroll
  for (int a = 0; a < 2; ++a)
#pragma unroll
    for (int b = 0; b < 10; ++b) acc[a][b] = (f32x4)(0.f);

  stage_chunk(W2ch, Wb0, w, lane);
  short8 a0 = *(const short8*)h0;
  short8 a1 = *(const short8*)h1;

#pragma unroll
  for (int c = 0; c < NKC2; ++c) {
    __syncthreads();
    if (c < NKC2 - 1)
      stage_chunk(W2ch + (size_t)(c + 1) * WCHU, (c & 1) ? Wb0 : Wb1, w, lane);
    const ushort* wb = (c & 1) ? Wb1 : Wb0;
#pragma unroll
    for (int ct = 0; ct < 10; ++ct) {
      const short8 bh = *(const short8*)&wb[lbase + ct * 512];
      const short8 bl = *(const short8*)&wb[lbase + ct * 512 + 5120];
      acc[0][ct] = mfma16(a0, bh, acc[0][ct]);
      acc[1][ct] = mfma16(a1, bh, acc[1][ct]);
      acc[0][ct] = mfma16(a0, bl, acc[0][ct]);
      acc[1][ct] = mfma16(a1, bl, acc[1][ct]);
    }
    if (c < NKC2 - 1) {
      a0 = *(const short8*)(h0 + (c + 1) * 32);
      a1 = *(const short8*)(h1 + (c + 1) * 32);
    }
  }
  const float b3v = b3[0];
#pragma unroll
  for (int rt = 0; rt < 2; ++rt)
#pragma unroll
    for (int q = 0; q < 4; ++q) {
      float s = 0.f;
#pragma unroll
      for (int ct = 0; ct < 10; ++ct) {
        const int col = ct * 16 + l15;
        s = fmaf(fmaxf(acc[rt][ct][q] + b2f[col], 0.f), W3f[col], s);
      }
      s += __shfl_xor(s, 1); s += __shfl_xor(s, 2);
      s += __shfl_xor(s, 4); s += __shfl_xor(s, 8);
      if (l15 == 0) {
        const int gr = r0 + w * 32 + rt * 16 + kb * 4 + q;
        if (gr < NP) out[gr] = s + b3v;
      }
    }
}

extern "C" void kernel_launch(void* const* d_in, const int* in_sizes, int n_in,
                              void* d_out, int out_size, void* d_ws, size_t ws_size,
                              hipStream_t stream) {
  const float* M    = (const float*)d_in[0];
  const int*   pidx = (const int*)d_in[1];
  const float* W1   = (const float*)d_in[3];
  const float* b1   = (const float*)d_in[4];
  const float* W2   = (const float*)d_in[5];
  const float* b2   = (const float*)d_in[6];
  const float* W3   = (const float*)d_in[7];
  const float* b3   = (const float*)d_in[8];
  float* out = (float*)d_out;

  const int P = in_sizes[1];
  const int NP = out_size;
  int K = 50;
  for (int k = 1; k <= P; ++k) {
    const long long np = (long long)k * (k - 1) / 2 + (long long)(P - k) * k;
    if (np == (long long)NP) { K = k; break; }
  }
  const int nb = (NP + ROWS - 1) / ROWS;

  // ws: G [P][1216] f32 | AB [2][P][160] f32 | W1ch 3*38*10240 us | W2ch 5*10240 us | H1 [nb*128][160] us
  float* G = (float*)d_ws;
  float* AB = G + (size_t)P * DP;
  ushort* W1ch = (ushort*)(AB + (size_t)2 * P * HPAD);
  ushort* W2ch = W1ch + (size_t)3 * NKC * WCHU;
  ushort* H1 = W2ch + (size_t)NKC2 * WCHU;

  const int prepN = 3 * NKC * HPAD * 32 + NKC2 * HPAD * 32;
  k_prep<<<(prepN + 255) / 256, 256, 0, stream>>>(W1, W2, W1ch, W2ch);
  k_gather<<<P, 256, 0, stream>>>(M, pidx, G);
  dim3 gp((P + ROWS - 1) / ROWS, 2);
  k_precomp<<<gp, 256, 0, stream>>>(G, W1ch, b1, AB, P);
  k_pair_l1<<<nb, 256, 0, stream>>>(G, W1ch, AB, H1, P, K, NP);
  k_mlp<<<nb, 256, 0, stream>>>(H1, W2ch, b2, W3, b3, out, NP);
}